// Round 6
// baseline (335.424 us; speedup 1.0000x reference)
//
#include <hip/hip_runtime.h>
#include <stdint.h>

// PennSkipGramModel forward.
// R1-R5 evidence: straight gather converges at 2.4-2.6 TB/s (scattered 512B
// granules), 90 us. But loss = (1/B) * sum of 786432 INDEPENDENT dot-terms
// (order-free), so we can re-order terms by v-row to fix the DRAM pattern:
//   pass 1 (scatter): bin terms by v_row>>5 (16KB v-range per bin).
//   pass 2 (main):    one block per bin -> v reads bin-local (each distinct
//                     v row fetched once, sequential-ish); u reads via L3.
// Falls back to the proven 90us direct kernel if ws_size is insufficient.

#define HV4   32         // float4s per 128-float row
#define HV    128
#define BATCH 65536
#define K     5
#define S     (BATCH * (1 + K))   // 393216 terms per stream
#define NB    3125                // bins per stream (32 rows/bin, 100000 rows)
#define NBT   (2 * NB)            // 6250 bins total
#define CAP   256                 // entries per bin (avg 126, +11.6 sigma)
#define CNT_BYTES   (NBT * 4)
#define ENT_OFFSET  65536         // entries start at ws+64KB (alignment)
#define WS_NEEDED   (ENT_OFFSET + (size_t)NBT * CAP * 8)

__device__ __forceinline__ float dot4(float4 a, float4 b) {
    return a.x * b.x + a.y * b.y + a.z * b.z + a.w * b.w;
}
__device__ __forceinline__ float red16(float v) {
    v += __shfl_xor(v, 8, 16);
    v += __shfl_xor(v, 4, 16);
    v += __shfl_xor(v, 2, 16);
    v += __shfl_xor(v, 1, 16);
    return v;
}
__device__ __forceinline__ float clip10(float x) {
    return fminf(fmaxf(x, -10.0f), 10.0f);
}

// ---------- pass 1: bin all 786432 terms by v-row ----------
__global__ __launch_bounds__(256) void scatter_terms(
    const int* __restrict__ pos_u, const int* __restrict__ pos_vl,
    const int* __restrict__ pos_vr, const int* __restrict__ neg_vl,
    const int* __restrict__ neg_vr, int* __restrict__ cnt,
    uint2* __restrict__ entries)
{
    const int t = blockIdx.x * 256 + threadIdx.x;   // 0 .. 2S-1
    const int s = (t >= S) ? 1 : 0;                 // 0=left stream, 1=right
    const int e = t - s * S;
    const int* pv = s ? pos_vr : pos_vl;
    const int* nv = s ? neg_vr : neg_vl;

    int row, u, neg;
    if (e < BATCH) { row = pv[e]; u = pos_u[e]; neg = 0; }
    else {
        const int j = e - BATCH;                    // 0 .. B*K-1
        row = nv[j]; u = pos_u[j / K]; neg = 1;
    }
    const int bin = s * NB + (row >> 5);
    const int slot = atomicAdd(&cnt[bin], 1);
    if (slot < CAP)
        entries[(size_t)bin * CAP + slot] =
            make_uint2((unsigned)row, ((unsigned)u << 1) | (unsigned)neg);
}

// ---------- pass 2: one block per bin; v reads bin-local ----------
__global__ __launch_bounds__(256) void binned_dots(
    const float* __restrict__ u_l, const float* __restrict__ u_r,
    const float* __restrict__ v_l, const float* __restrict__ v_r,
    const int* __restrict__ cnt, const uint2* __restrict__ entries,
    float* __restrict__ out)
{
    const int tid  = threadIdx.x;
    const int lane = tid & 15;
    const int grp  = tid >> 4;          // 16 groups of 16 lanes
    const int bin  = blockIdx.x;
    const int s    = (bin >= NB) ? 1 : 0;
    const float* vt = s ? v_r : v_l;
    const float* ut = s ? u_r : u_l;

    const int n = min(cnt[bin], CAP);
    const uint2* eb = entries + (size_t)bin * CAP;

    float acc = 0.0f;
    for (int i = grp; i < n; i += 16) {
        const uint2 e = eb[i];
        const int row =  (int)e.x;
        const int uix =  (int)(e.y >> 1);
        const int neg =  (int)(e.y & 1u);
        const float4* V = (const float4*)vt + (size_t)row * HV4;
        const float4* U = (const float4*)ut + (size_t)uix * HV4;
        float4 v0 = V[lane], v1 = V[lane + 16];
        float4 u0 = U[lane], u1 = U[lane + 16];
        const float d = red16(dot4(u0, v0) + dot4(u1, v1));
        const float c = clip10(d);
        // pos term: -logsig(c) = log(1+exp(-c)); neg term: log(1+exp(c))
        acc += __logf(1.0f + __expf(neg ? c : -c));
    }

    __shared__ float smem[16];
    if (lane == 0) smem[grp] = acc;     // all 16 lanes of a group hold same acc
    __syncthreads();
    if (tid == 0) {
        float ssum = 0.0f;
        #pragma unroll
        for (int i = 0; i < 16; ++i) ssum += smem[i];
        atomicAdd(out, ssum * (1.0f / BATCH));
    }
}

// ---------- fallback: proven 90us direct-gather kernel ----------
__global__ __launch_bounds__(256) void skipgram_fwd(
    const float* __restrict__ u_l, const float* __restrict__ u_r,
    const float* __restrict__ v_l, const float* __restrict__ v_r,
    const int* __restrict__ pos_u, const int* __restrict__ pos_vl,
    const int* __restrict__ pos_vr, const int* __restrict__ neg_vl,
    const int* __restrict__ neg_vr, float* __restrict__ out)
{
    const int tid  = threadIdx.x;
    const int lane = tid & 15;
    const int grp  = tid >> 4;
    const int b    = (blockIdx.x << 4) + grp;

    const int iu  = pos_u[b];
    const int ivl = pos_vl[b];
    const int ivr = pos_vr[b];

    const float4* ULr = (const float4*)u_l + (size_t)iu * HV4;
    const float4* URr = (const float4*)u_r + (size_t)iu * HV4;
    float4 ul0 = ULr[lane], ul1 = ULr[lane + 16];
    float4 ur0 = URr[lane], ur1 = URr[lane + 16];

    const float4* VLr = (const float4*)v_l + (size_t)ivl * HV4;
    const float4* VRr = (const float4*)v_r + (size_t)ivr * HV4;
    float4 vl0 = VLr[lane], vl1 = VLr[lane + 16];
    float4 vr0 = VRr[lane], vr1 = VRr[lane + 16];

    float sl = red16(dot4(ul0, vl0) + dot4(ul1, vl1));
    float sr = red16(dot4(ur0, vr0) + dot4(ur1, vr1));
    float acc = __logf(1.0f + __expf(-clip10(sl)))
              + __logf(1.0f + __expf(-clip10(sr)));

    #pragma unroll
    for (int k = 0; k < K; ++k) {
        const int inl = neg_vl[b * K + k];
        const int inr = neg_vr[b * K + k];
        const float4* NL = (const float4*)v_l + (size_t)inl * HV4;
        const float4* NR = (const float4*)v_r + (size_t)inr * HV4;
        float4 nl0 = NL[lane], nl1 = NL[lane + 16];
        float4 nr0 = NR[lane], nr1 = NR[lane + 16];
        float snl = red16(dot4(ul0, nl0) + dot4(ul1, nl1));
        float snr = red16(dot4(ur0, nr0) + dot4(ur1, nr1));
        acc += __logf(1.0f + __expf(clip10(snl)))
             + __logf(1.0f + __expf(clip10(snr)));
    }

    __shared__ float smem[16];
    if (lane == 0) smem[grp] = acc;
    __syncthreads();
    if (tid == 0) {
        float ssum = 0.0f;
        #pragma unroll
        for (int i = 0; i < 16; ++i) ssum += smem[i];
        atomicAdd(out, ssum * (1.0f / BATCH));
    }
}

extern "C" void kernel_launch(void* const* d_in, const int* in_sizes, int n_in,
                              void* d_out, int out_size, void* d_ws, size_t ws_size,
                              hipStream_t stream) {
    const float* u_l   = (const float*)d_in[0];
    const float* u_r   = (const float*)d_in[1];
    const float* v_l   = (const float*)d_in[2];
    const float* v_r   = (const float*)d_in[3];
    const int* pos_u   = (const int*)d_in[4];
    const int* pos_vl  = (const int*)d_in[5];
    const int* pos_vr  = (const int*)d_in[6];
    const int* neg_vl  = (const int*)d_in[7];
    const int* neg_vr  = (const int*)d_in[8];
    float* out = (float*)d_out;

    hipMemsetAsync(out, 0, sizeof(float), stream);

    if (ws_size >= WS_NEEDED) {
        int*   cnt     = (int*)d_ws;
        uint2* entries = (uint2*)((char*)d_ws + ENT_OFFSET);
        hipMemsetAsync(cnt, 0, CNT_BYTES, stream);
        scatter_terms<<<(2 * S) / 256, 256, 0, stream>>>(
            pos_u, pos_vl, pos_vr, neg_vl, neg_vr, cnt, entries);
        binned_dots<<<NBT, 256, 0, stream>>>(
            u_l, u_r, v_l, v_r, cnt, entries, out);
    } else {
        skipgram_fwd<<<BATCH / 16, 256, 0, stream>>>(
            u_l, u_r, v_l, v_r, pos_u, pos_vl, pos_vr, neg_vl, neg_vr, out);
    }
}